// Round 6
// baseline (82.472 us; speedup 1.0000x reference)
//
#include <hip/hip_runtime.h>
#include <math.h>

#define B 8
#define NQ 2048
#define NK 2048
#define CIN 64
#define COUT 64

constexpr float LOG2E = 1.44269504088896340736f;

typedef __attribute__((ext_vector_type(8))) short bf16x8;
typedef __attribute__((ext_vector_type(4))) float f32x4;

__device__ __forceinline__ unsigned short f2bf(float x) {   // RNE f32->bf16
    union { float f; unsigned u; } v; v.f = x;
    return (unsigned short)((v.u + 0x7FFFu + ((v.u >> 16) & 1u)) >> 16);
}

// ---------------- pre-pass: V -> Vt bf16 (transposed) + score coefficients ---
__global__ __launch_bounds__(256) void setconv_prepass(
    const float* __restrict__ keys,     // [B][NK][2]
    const float* __restrict__ values,   // [B][NK][CIN]
    const float* __restrict__ wW,
    const float* __restrict__ lsp,
    unsigned short* __restrict__ vt,    // [B][CIN][NK] bf16
    float4* __restrict__ coeff)         // [B][NK] (atil, btil, ekl, 0)
{
    __shared__ float lds[64][65];
    const int t   = threadIdx.x;
    const int bid = blockIdx.x;         // 256 = 8 batches x 32 k-tiles
    const int b   = bid & 7;
    const int kt  = bid >> 3;

    // load 64k x 64c f32 tile, coalesced
    {
        const float* vbase = values + ((size_t)b * NK + (size_t)kt * 64) * CIN;
        const int r  = t >> 2;
        const int cq = t & 3;
        #pragma unroll
        for (int i = 0; i < 4; ++i) {
            const float4 v = *reinterpret_cast<const float4*>(
                vbase + r * CIN + cq * 16 + i * 4);
            lds[r][cq * 16 + i * 4 + 0] = v.x;
            lds[r][cq * 16 + i * 4 + 1] = v.y;
            lds[r][cq * 16 + i * 4 + 2] = v.z;
            lds[r][cq * 16 + i * 4 + 3] = v.w;
        }
    }

    // score coefficients for this tile's 64 keys
    if (t < 64) {
        const float W00 = wW[0], W01 = wW[1], W10 = wW[2], W11 = wW[3];
        const float xls = lsp[0] * 0.1f - 1.0f;
        const float sp  = (xls > 20.f) ? xls : log1pf(__expf(xls));
        const float sg  = 1e-5f + sp;
        const float s2  = (-0.5f / (sg * sg)) * LOG2E;
        const int   k   = kt * 64 + t;
        const float2 kv = reinterpret_cast<const float2*>(keys + (size_t)b * NK * 2)[k];
        const float a   = W00 * kv.x + W01 * kv.y;
        const float bb  = W10 * kv.x + W11 * kv.y;
        float4 cf;
        cf.x = -2.f * s2 * a;
        cf.y = -2.f * s2 * bb;
        cf.z = s2 * (a * a + bb * bb);
        cf.w = 0.f;
        coeff[(size_t)b * NK + k] = cf;
    }
    __syncthreads();

    // write transposed bf16: vt[b][c][kt*64 + kq*16 .. +15]
    {
        const int c  = t >> 2;
        const int kq = t & 3;
        unsigned pack[8];
        #pragma unroll
        for (int i = 0; i < 8; ++i) {
            const unsigned lo = f2bf(lds[kq * 16 + 2 * i + 0][c]);
            const unsigned hi = f2bf(lds[kq * 16 + 2 * i + 1][c]);
            pack[i] = lo | (hi << 16);
        }
        uint4* d4 = reinterpret_cast<uint4*>(
            vt + ((size_t)b * CIN + c) * NK + (size_t)kt * 64 + kq * 16);
        d4[0] = make_uint4(pack[0], pack[1], pack[2], pack[3]);
        d4[1] = make_uint4(pack[4], pack[5], pack[6], pack[7]);
    }
}

// ---------------- main kernel: 512 blocks x 32 queries, k split 4-way --------
#define SCORE(J, EV)                                              \
    float EV;                                                     \
    {                                                             \
        const float4 cf = cp[J];                                  \
        float t_ = cf.z + Fq;                                     \
        t_ = fmaf(cf.y, bq, t_);                                  \
        t_ = fmaf(cf.x, aq, t_);                                  \
        EV = exp2f(t_);                                           \
    }

#define BLOAD(BF, CT)                                             \
    const bf16x8 BF = *reinterpret_cast<const bf16x8*>(           \
        vt + ((size_t)b * CIN + (CT) * 16 + l15) * NK + kb);

__global__ __launch_bounds__(512, 4) void setconv_main(
    const float* __restrict__ queries,  // [B][NQ][2]
    const float* __restrict__ wW,
    const float* __restrict__ lsp,
    const float* __restrict__ dW,
    const float* __restrict__ db,
    const float* __restrict__ rW,       // [COUT][CIN+1]
    const float* __restrict__ rb,       // [COUT]
    const unsigned short* __restrict__ vt,
    const float4* __restrict__ coeff,
    float* __restrict__ out)            // [B][NQ][COUT]
{
    __shared__ float pt[4][32][66];     // per-wg partial P*V (33.8 KB)
    __shared__ float esp[4][32];
    __shared__ float qinfo[32][2];      // inv_esum, density

    const int tid  = threadIdx.x;
    const int wave = tid >> 6;
    const int lane = tid & 63;
    const int g    = lane >> 4;
    const int l15  = lane & 15;
    const int wg   = wave >> 1;         // 0..3: k-group
    const int rt   = wave & 1;          // 0..1: 16-query row tile

    const int bid = blockIdx.x;         // 512 = 8 batches x 64 q-tiles
    const int b   = bid & 7;
    const int q0  = (bid >> 3) * 32;

    // per-lane query coefficients
    const float W00 = wW[0], W01 = wW[1], W10 = wW[2], W11 = wW[3];
    const float xls = lsp[0] * 0.1f - 1.0f;
    const float sp  = (xls > 20.f) ? xls : log1pf(__expf(xls));
    const float sg  = 1e-5f + sp;
    const float s2  = (-0.5f / (sg * sg)) * LOG2E;
    const int   q   = q0 + rt * 16 + l15;
    const float2 qv = reinterpret_cast<const float2*>(queries + (size_t)b * NQ * 2)[q];
    const float aq  = W00 * qv.x + W01 * qv.y;
    const float bq  = W10 * qv.x + W11 * qv.y;
    const float Fq  = s2 * (aq * aq + bq * bq);

    f32x4 c0 = {0.f, 0.f, 0.f, 0.f};
    f32x4 c1 = c0, c2 = c0, c3 = c0, ce = c0;
    const bf16x8 ones = { (short)0x3F80, (short)0x3F80, (short)0x3F80, (short)0x3F80,
                          (short)0x3F80, (short)0x3F80, (short)0x3F80, (short)0x3F80 };

    #pragma unroll 2
    for (int it = 0; it < NK / 128; ++it) {
        const int kb = it * 128 + wg * 32 + g * 8;
        const float4* cp = coeff + (size_t)b * NK + kb;

        SCORE(0, e0) SCORE(1, e1) SCORE(2, e2) SCORE(3, e3)
        SCORE(4, e4) SCORE(5, e5) SCORE(6, e6) SCORE(7, e7)
        bf16x8 af;
        af[0] = (short)f2bf(e0); af[1] = (short)f2bf(e1);
        af[2] = (short)f2bf(e2); af[3] = (short)f2bf(e3);
        af[4] = (short)f2bf(e4); af[5] = (short)f2bf(e5);
        af[6] = (short)f2bf(e6); af[7] = (short)f2bf(e7);

        BLOAD(b0, 0) BLOAD(b1, 1) BLOAD(b2, 2) BLOAD(b3, 3)

        c0 = __builtin_amdgcn_mfma_f32_16x16x32_bf16(af, b0, c0, 0, 0, 0);
        c1 = __builtin_amdgcn_mfma_f32_16x16x32_bf16(af, b1, c1, 0, 0, 0);
        c2 = __builtin_amdgcn_mfma_f32_16x16x32_bf16(af, b2, c2, 0, 0, 0);
        c3 = __builtin_amdgcn_mfma_f32_16x16x32_bf16(af, b3, c3, 0, 0, 0);
        ce = __builtin_amdgcn_mfma_f32_16x16x32_bf16(af, ones, ce, 0, 0, 0);
    }

    // write per-wg partials.  C/D layout: col = l15, row = g*4 + reg
    #define STORE_R(R)                                                        \
    {                                                                         \
        const int qq = rt * 16 + g * 4 + (R);                                 \
        pt[wg][qq][0 * 16 + l15] = c0[R];                                     \
        pt[wg][qq][1 * 16 + l15] = c1[R];                                     \
        pt[wg][qq][2 * 16 + l15] = c2[R];                                     \
        pt[wg][qq][3 * 16 + l15] = c3[R];                                     \
        if (l15 == 0) esp[wg][qq] = ce[R];                                    \
    }
    STORE_R(0) STORE_R(1) STORE_R(2) STORE_R(3)
    __syncthreads();

    // combine 4 k-groups
    #pragma unroll
    for (int rr = 0; rr < 4; ++rr) {
        const int p  = tid + rr * 512;
        const int qq = p >> 6;
        const int cc = p & 63;
        const float s = pt[0][qq][cc] + pt[1][qq][cc] + pt[2][qq][cc] + pt[3][qq][cc];
        pt[0][qq][cc] = s;
    }
    if (tid < 32) {
        const float s = esp[0][tid] + esp[1][tid] + esp[2][tid] + esp[3][tid];
        const float arg = ((-s) * dW[0] + db[0]) * 0.1f;
        qinfo[tid][1] = 1.f / (1.f + __expf(-arg));   // density channel
        qinfo[tid][0] = 1.f / s;                      // softmax denom
    }
    __syncthreads();

    // fused resizer epilogue
    {
        const int qq   = tid >> 4;                // 0..31
        const float invE = qinfo[qq][0];
        const float dens = qinfo[qq][1];
        float* orow = out + (size_t)(b * NQ + q0 + qq) * COUT;
        #pragma unroll
        for (int r = 0; r < 4; ++r) {
            const int o = (tid & 15) + r * 16;
            const float* wrow = rW + o * (CIN + 1);
            float sdot = 0.f;
            #pragma unroll 8
            for (int c = 0; c < CIN; ++c) sdot += pt[0][qq][c] * wrow[c];
            orow[o] = rb[o] + dens * wrow[CIN] + sdot * invE;
        }
    }
}

// ---------------- fallback (round-5 kernel, used if ws too small) -----------
#define FSCORE(J, EV)                                             \
    float EV;                                                     \
    {                                                             \
        float t_ = ekl[kb + (J)] + Fq;                            \
        t_ = fmaf(btil[kb + (J)], bq, t_);                        \
        t_ = fmaf(atil[kb + (J)], aq, t_);                        \
        EV = exp2f(t_);                                           \
    }
#define FBLOAD(BF, CT)                                            \
    bf16x8 BF;                                                    \
    BF[0] = (short)f2bf(pB[0 * CIN + (CT) * 16]);                 \
    BF[1] = (short)f2bf(pB[1 * CIN + (CT) * 16]);                 \
    BF[2] = (short)f2bf(pB[2 * CIN + (CT) * 16]);                 \
    BF[3] = (short)f2bf(pB[3 * CIN + (CT) * 16]);                 \
    BF[4] = (short)f2bf(pB[4 * CIN + (CT) * 16]);                 \
    BF[5] = (short)f2bf(pB[5 * CIN + (CT) * 16]);                 \
    BF[6] = (short)f2bf(pB[6 * CIN + (CT) * 16]);                 \
    BF[7] = (short)f2bf(pB[7 * CIN + (CT) * 16]);

__global__ __launch_bounds__(512) void setconv_mfma_fb(
    const float* __restrict__ keys, const float* __restrict__ queries,
    const float* __restrict__ values, const float* __restrict__ wW,
    const float* __restrict__ lsp, const float* __restrict__ dW,
    const float* __restrict__ db, const float* __restrict__ rW,
    const float* __restrict__ rb, float* __restrict__ out)
{
    __shared__ float atil[NK];
    __shared__ float btil[NK];
    __shared__ float ekl[NK];
    __shared__ float tot[64][66];
    __shared__ float esum_lds[64];
    __shared__ float qinfo[64][2];

    const int tid  = threadIdx.x;
    const int wave = tid >> 6;
    const int lane = tid & 63;
    const int g    = lane >> 4;
    const int l15  = lane & 15;
    const int wg   = wave >> 2;
    const int rt   = wave & 3;
    const int bid  = blockIdx.x;
    const int b    = bid & 7;
    const int q0   = (bid >> 3) * 64;

    const float W00 = wW[0], W01 = wW[1], W10 = wW[2], W11 = wW[3];
    const float xls = lsp[0] * 0.1f - 1.0f;
    const float sp  = (xls > 20.f) ? xls : log1pf(__expf(xls));
    const float sg  = 1e-5f + sp;
    const float s2  = (-0.5f / (sg * sg)) * LOG2E;

    {
        const float2* kb2 = (const float2*)(keys + (size_t)b * NK * 2);
        #pragma unroll
        for (int it = 0; it < NK / 512; ++it) {
            const int k = tid + it * 512;
            const float2 kv = kb2[k];
            const float a  = W00 * kv.x + W01 * kv.y;
            const float bb = W10 * kv.x + W11 * kv.y;
            atil[k] = -2.f * s2 * a;
            btil[k] = -2.f * s2 * bb;
            ekl[k]  = s2 * (a * a + bb * bb);
        }
    }
    const int q = q0 + rt * 16 + l15;
    const float2 qv = ((const float2*)(queries + (size_t)b * NQ * 2))[q];
    const float aq = W00 * qv.x + W01 * qv.y;
    const float bq = W10 * qv.x + W11 * qv.y;
    const float Fq = s2 * (aq * aq + bq * bq);
    __syncthreads();

    f32x4 c0 = {0.f, 0.f, 0.f, 0.f};
    f32x4 c1 = c0, c2 = c0, c3 = c0, ce = c0;
    const bf16x8 ones = { (short)0x3F80, (short)0x3F80, (short)0x3F80, (short)0x3F80,
                          (short)0x3F80, (short)0x3F80, (short)0x3F80, (short)0x3F80 };
    const float* vb = values + (size_t)b * NK * CIN;

    #pragma unroll 1
    for (int it = 0; it < NK / 64; ++it) {
        const int kb = it * 64 + wg * 32 + g * 8;
        FSCORE(0, e0) FSCORE(1, e1) FSCORE(2, e2) FSCORE(3, e3)
        FSCORE(4, e4) FSCORE(5, e5) FSCORE(6, e6) FSCORE(7, e7)
        bf16x8 af;
        af[0] = (short)f2bf(e0); af[1] = (short)f2bf(e1);
        af[2] = (short)f2bf(e2); af[3] = (short)f2bf(e3);
        af[4] = (short)f2bf(e4); af[5] = (short)f2bf(e5);
        af[6] = (short)f2bf(e6); af[7] = (short)f2bf(e7);
        const float* pB = vb + (size_t)kb * CIN + l15;
        FBLOAD(b0, 0) FBLOAD(b1, 1) FBLOAD(b2, 2) FBLOAD(b3, 3)
        c0 = __builtin_amdgcn_mfma_f32_16x16x32_bf16(af, b0, c0, 0, 0, 0);
        c1 = __builtin_amdgcn_mfma_f32_16x16x32_bf16(af, b1, c1, 0, 0, 0);
        c2 = __builtin_amdgcn_mfma_f32_16x16x32_bf16(af, b2, c2, 0, 0, 0);
        c3 = __builtin_amdgcn_mfma_f32_16x16x32_bf16(af, b3, c3, 0, 0, 0);
        ce = __builtin_amdgcn_mfma_f32_16x16x32_bf16(af, ones, ce, 0, 0, 0);
    }
    #define FSTORE_R(R)                                                       \
    {                                                                         \
        const int qq = rt * 16 + g * 4 + (R);                                 \
        tot[qq][0 * 16 + l15] = c0[R];                                        \
        tot[qq][1 * 16 + l15] = c1[R];                                        \
        tot[qq][2 * 16 + l15] = c2[R];                                        \
        tot[qq][3 * 16 + l15] = c3[R];                                        \
        if (l15 == 0) esum_lds[qq] = ce[R];                                   \
    }
    #define FADD_R(R)                                                         \
    {                                                                         \
        const int qq = rt * 16 + g * 4 + (R);                                 \
        tot[qq][0 * 16 + l15] += c0[R];                                       \
        tot[qq][1 * 16 + l15] += c1[R];                                       \
        tot[qq][2 * 16 + l15] += c2[R];                                       \
        tot[qq][3 * 16 + l15] += c3[R];                                       \
        if (l15 == 0) esum_lds[qq] += ce[R];                                  \
    }
    if (wg == 0) { FSTORE_R(0) FSTORE_R(1) FSTORE_R(2) FSTORE_R(3) }
    __syncthreads();
    if (wg == 1) { FADD_R(0) FADD_R(1) FADD_R(2) FADD_R(3) }
    __syncthreads();
    if (tid < 64) {
        const float s = esum_lds[tid];
        const float arg = ((-s) * dW[0] + db[0]) * 0.1f;
        qinfo[tid][1] = 1.f / (1.f + __expf(-arg));
        qinfo[tid][0] = 1.f / s;
    }
    __syncthreads();
    {
        const int qq   = tid >> 3;
        const float invE = qinfo[qq][0];
        const float dens = qinfo[qq][1];
        float* orow = out + (size_t)(b * NQ + q0 + qq) * COUT;
        #pragma unroll
        for (int r = 0; r < 8; ++r) {
            const int o = (tid & 7) + r * 8;
            const float* wrow = rW + o * (CIN + 1);
            float sdot = 0.f;
            #pragma unroll 8
            for (int c = 0; c < CIN; ++c) sdot += tot[qq][c] * wrow[c];
            orow[o] = rb[o] + dens * wrow[CIN] + sdot * invE;
        }
    }
}

extern "C" void kernel_launch(void* const* d_in, const int* in_sizes, int n_in,
                              void* d_out, int out_size, void* d_ws, size_t ws_size,
                              hipStream_t stream) {
    const float* keys    = (const float*)d_in[0];
    const float* queries = (const float*)d_in[1];
    const float* values  = (const float*)d_in[2];
    const float* wW      = (const float*)d_in[3];
    const float* lsp     = (const float*)d_in[4];
    const float* dW      = (const float*)d_in[5];
    const float* db      = (const float*)d_in[6];
    const float* rW      = (const float*)d_in[7];
    const float* rb      = (const float*)d_in[8];
    float* out = (float*)d_out;

    const size_t VT_BYTES    = (size_t)B * CIN * NK * 2;        // 2 MB
    const size_t COEFF_BYTES = (size_t)B * NK * 16;             // 256 KB
    const size_t NEED        = VT_BYTES + COEFF_BYTES;

    if (ws_size >= NEED) {
        unsigned short* vt = (unsigned short*)d_ws;
        float4* coeff = (float4*)((char*)d_ws + VT_BYTES);
        setconv_prepass<<<dim3(256), 256, 0, stream>>>(keys, values, wW, lsp, vt, coeff);
        setconv_main<<<dim3(512), 512, 0, stream>>>(queries, wW, lsp, dW, db,
                                                    rW, rb, vt, coeff, out);
    } else {
        setconv_mfma_fb<<<dim3(256), 512, 0, stream>>>(keys, queries, values, wW,
                                                       lsp, dW, db, rW, rb, out);
    }
}

// Round 7
// 68.800 us; speedup vs baseline: 1.1987x; 1.1987x over previous
//
#include <hip/hip_runtime.h>
#include <math.h>

#define B 8
#define NQ 2048
#define NK 2048
#define CIN 64
#define COUT 64

constexpr float LOG2E = 1.44269504088896340736f;

typedef __attribute__((ext_vector_type(8))) short bf16x8;
typedef __attribute__((ext_vector_type(4))) float f32x4;

__device__ __forceinline__ unsigned short f2bf(float x) {   // RNE f32->bf16
    union { float f; unsigned u; } v; v.f = x;
    return (unsigned short)((v.u + 0x7FFFu + ((v.u >> 16) & 1u)) >> 16);
}

// ------- pre-pass: V -> Vfrag[b][k/32][c][k%32] bf16 + score coefficients ---
__global__ __launch_bounds__(256) void setconv_prepass(
    const float* __restrict__ keys,     // [B][NK][2]
    const float* __restrict__ values,   // [B][NK][CIN]
    const float* __restrict__ wW,
    const float* __restrict__ lsp,
    unsigned short* __restrict__ vf,    // [B][NK/32][CIN][32] bf16
    float4* __restrict__ coeff)         // [B][NK] (atil, btil, ekl, 0)
{
    __shared__ float lds[64][65];
    const int t   = threadIdx.x;
    const int bid = blockIdx.x;         // 256 = 8 batches x 32 k-tiles(64)
    const int b   = bid & 7;
    const int kt  = bid >> 3;

    // load 64k x 64c f32 tile, coalesced
    {
        const float* vbase = values + ((size_t)b * NK + (size_t)kt * 64) * CIN;
        const int r  = t >> 2;
        const int cq = t & 3;
        #pragma unroll
        for (int i = 0; i < 4; ++i) {
            const float4 v = *reinterpret_cast<const float4*>(
                vbase + r * CIN + cq * 16 + i * 4);
            lds[r][cq * 16 + i * 4 + 0] = v.x;
            lds[r][cq * 16 + i * 4 + 1] = v.y;
            lds[r][cq * 16 + i * 4 + 2] = v.z;
            lds[r][cq * 16 + i * 4 + 3] = v.w;
        }
    }

    // score coefficients for this tile's 64 keys
    if (t < 64) {
        const float W00 = wW[0], W01 = wW[1], W10 = wW[2], W11 = wW[3];
        const float xls = lsp[0] * 0.1f - 1.0f;
        const float sp  = (xls > 20.f) ? xls : log1pf(__expf(xls));
        const float sg  = 1e-5f + sp;
        const float s2  = (-0.5f / (sg * sg)) * LOG2E;
        const int   k   = kt * 64 + t;
        const float2 kv = reinterpret_cast<const float2*>(keys + (size_t)b * NK * 2)[k];
        const float a   = W00 * kv.x + W01 * kv.y;
        const float bb  = W10 * kv.x + W11 * kv.y;
        float4 cf;
        cf.x = -2.f * s2 * a;
        cf.y = -2.f * s2 * bb;
        cf.z = s2 * (a * a + bb * bb);
        cf.w = 0.f;
        coeff[(size_t)b * NK + k] = cf;
    }
    __syncthreads();

    // write fragment layout: vf[b][kt*2 + (kq>>1)][c][(kq&1)*16 + i], i=0..15
    {
        const int c  = t >> 2;           // 0..63
        const int kq = t & 3;            // 0..3 -> k-local range kq*16..+15
        unsigned pack[8];
        #pragma unroll
        for (int i = 0; i < 8; ++i) {
            const unsigned lo = f2bf(lds[kq * 16 + 2 * i + 0][c]);
            const unsigned hi = f2bf(lds[kq * 16 + 2 * i + 1][c]);
            pack[i] = lo | (hi << 16);
        }
        const size_t kblk = (size_t)kt * 2 + (kq >> 1);
        uint4* d4 = reinterpret_cast<uint4*>(
            vf + (((size_t)b * (NK / 32) + kblk) * CIN + c) * 32 + (kq & 1) * 16);
        d4[0] = make_uint4(pack[0], pack[1], pack[2], pack[3]);
        d4[1] = make_uint4(pack[4], pack[5], pack[6], pack[7]);
    }
}

// ---------------- main kernel: 512 blocks x 32 queries, k split 4-way --------
#define SCORE(J, EV)                                              \
    float EV;                                                     \
    {                                                             \
        const float4 cf = cp[J];                                  \
        float t_ = cf.z + Fq;                                     \
        t_ = fmaf(cf.y, bq, t_);                                  \
        t_ = fmaf(cf.x, aq, t_);                                  \
        EV = exp2f(t_);                                           \
    }

// fragment-native: wave reads 1KB contiguous (lane addr = base + l15*64B + g*16B)
#define BLOAD(BF, CT)                                             \
    const bf16x8 BF = *reinterpret_cast<const bf16x8*>(           \
        vfb + ((size_t)kblk * CIN + (CT) * 16 + l15) * 32 + g * 8);

__global__ __launch_bounds__(512, 4) void setconv_main(
    const float* __restrict__ queries,  // [B][NQ][2]
    const float* __restrict__ wW,
    const float* __restrict__ lsp,
    const float* __restrict__ dW,
    const float* __restrict__ db,
    const float* __restrict__ rW,       // [COUT][CIN+1]
    const float* __restrict__ rb,       // [COUT]
    const unsigned short* __restrict__ vf,
    const float4* __restrict__ coeff,
    float* __restrict__ out)            // [B][NQ][COUT]
{
    __shared__ float pt[4][32][66];     // per-wg partial P*V (33.8 KB)
    __shared__ float esp[4][32];
    __shared__ float qinfo[32][2];      // inv_esum, density

    const int tid  = threadIdx.x;
    const int wave = tid >> 6;
    const int lane = tid & 63;
    const int g    = lane >> 4;
    const int l15  = lane & 15;
    const int wg   = wave >> 1;         // 0..3: k-group
    const int rt   = wave & 1;          // 0..1: 16-query row tile

    const int bid = blockIdx.x;         // 512 = 8 batches x 64 q-tiles
    const int b   = bid & 7;
    const int q0  = (bid >> 3) * 32;

    // per-lane query coefficients
    const float W00 = wW[0], W01 = wW[1], W10 = wW[2], W11 = wW[3];
    const float xls = lsp[0] * 0.1f - 1.0f;
    const float sp  = (xls > 20.f) ? xls : log1pf(__expf(xls));
    const float sg  = 1e-5f + sp;
    const float s2  = (-0.5f / (sg * sg)) * LOG2E;
    const int   q   = q0 + rt * 16 + l15;
    const float2 qv = reinterpret_cast<const float2*>(queries + (size_t)b * NQ * 2)[q];
    const float aq  = W00 * qv.x + W01 * qv.y;
    const float bq  = W10 * qv.x + W11 * qv.y;
    const float Fq  = s2 * (aq * aq + bq * bq);

    f32x4 c0 = {0.f, 0.f, 0.f, 0.f};
    f32x4 c1 = c0, c2 = c0, c3 = c0, ce = c0;
    const bf16x8 ones = { (short)0x3F80, (short)0x3F80, (short)0x3F80, (short)0x3F80,
                          (short)0x3F80, (short)0x3F80, (short)0x3F80, (short)0x3F80 };

    const unsigned short* vfb = vf + (size_t)b * (NK / 32) * CIN * 32;

    #pragma unroll 2
    for (int it = 0; it < NK / 128; ++it) {
        const int kb   = it * 128 + wg * 32 + g * 8;   // for coefficients
        const int kblk = it * 4 + wg;                  // 32-k block index
        const float4* cp = coeff + (size_t)b * NK + kb;

        SCORE(0, e0) SCORE(1, e1) SCORE(2, e2) SCORE(3, e3)
        SCORE(4, e4) SCORE(5, e5) SCORE(6, e6) SCORE(7, e7)
        bf16x8 af;
        af[0] = (short)f2bf(e0); af[1] = (short)f2bf(e1);
        af[2] = (short)f2bf(e2); af[3] = (short)f2bf(e3);
        af[4] = (short)f2bf(e4); af[5] = (short)f2bf(e5);
        af[6] = (short)f2bf(e6); af[7] = (short)f2bf(e7);

        BLOAD(b0, 0) BLOAD(b1, 1) BLOAD(b2, 2) BLOAD(b3, 3)

        c0 = __builtin_amdgcn_mfma_f32_16x16x32_bf16(af, b0, c0, 0, 0, 0);
        c1 = __builtin_amdgcn_mfma_f32_16x16x32_bf16(af, b1, c1, 0, 0, 0);
        c2 = __builtin_amdgcn_mfma_f32_16x16x32_bf16(af, b2, c2, 0, 0, 0);
        c3 = __builtin_amdgcn_mfma_f32_16x16x32_bf16(af, b3, c3, 0, 0, 0);
        ce = __builtin_amdgcn_mfma_f32_16x16x32_bf16(af, ones, ce, 0, 0, 0);
    }

    // write per-wg partials.  C/D layout: col = l15, row = g*4 + reg
    #define STORE_R(R)                                                        \
    {                                                                         \
        const int qq = rt * 16 + g * 4 + (R);                                 \
        pt[wg][qq][0 * 16 + l15] = c0[R];                                     \
        pt[wg][qq][1 * 16 + l15] = c1[R];                                     \
        pt[wg][qq][2 * 16 + l15] = c2[R];                                     \
        pt[wg][qq][3 * 16 + l15] = c3[R];                                     \
        if (l15 == 0) esp[wg][qq] = ce[R];                                    \
    }
    STORE_R(0) STORE_R(1) STORE_R(2) STORE_R(3)
    __syncthreads();

    // combine 4 k-groups
    #pragma unroll
    for (int rr = 0; rr < 4; ++rr) {
        const int p  = tid + rr * 512;
        const int qq = p >> 6;
        const int cc = p & 63;
        const float s = pt[0][qq][cc] + pt[1][qq][cc] + pt[2][qq][cc] + pt[3][qq][cc];
        pt[0][qq][cc] = s;
    }
    if (tid < 32) {
        const float s = esp[0][tid] + esp[1][tid] + esp[2][tid] + esp[3][tid];
        const float arg = ((-s) * dW[0] + db[0]) * 0.1f;
        qinfo[tid][1] = 1.f / (1.f + __expf(-arg));   // density channel
        qinfo[tid][0] = 1.f / s;                      // softmax denom
    }
    __syncthreads();

    // fused resizer epilogue
    {
        const int qq   = tid >> 4;                // 0..31
        const float invE = qinfo[qq][0];
        const float dens = qinfo[qq][1];
        float* orow = out + (size_t)(b * NQ + q0 + qq) * COUT;
        #pragma unroll
        for (int r = 0; r < 4; ++r) {
            const int o = (tid & 15) + r * 16;
            const float* wrow = rW + o * (CIN + 1);
            float sdot = 0.f;
            #pragma unroll 8
            for (int c = 0; c < CIN; ++c) sdot += pt[0][qq][c] * wrow[c];
            orow[o] = rb[o] + dens * wrow[CIN] + sdot * invE;
        }
    }
}

// ---------------- fallback (round-5 kernel, used if ws too small) -----------
#define FSCORE(J, EV)                                             \
    float EV;                                                     \
    {                                                             \
        float t_ = ekl[kb + (J)] + Fq;                            \
        t_ = fmaf(btil[kb + (J)], bq, t_);                        \
        t_ = fmaf(atil[kb + (J)], aq, t_);                        \
        EV = exp2f(t_);                                           \
    }
#define FBLOAD(BF, CT)                                            \
    bf16x8 BF;                                                    \
    BF[0] = (short)f2bf(pB[0 * CIN + (CT) * 16]);                 \
    BF[1] = (short)f2bf(pB[1 * CIN + (CT) * 16]);                 \
    BF[2] = (short)f2bf(pB[2 * CIN + (CT) * 16]);                 \
    BF[3] = (short)f2bf(pB[3 * CIN + (CT) * 16]);                 \
    BF[4] = (short)f2bf(pB[4 * CIN + (CT) * 16]);                 \
    BF[5] = (short)f2bf(pB[5 * CIN + (CT) * 16]);                 \
    BF[6] = (short)f2bf(pB[6 * CIN + (CT) * 16]);                 \
    BF[7] = (short)f2bf(pB[7 * CIN + (CT) * 16]);

__global__ __launch_bounds__(512) void setconv_mfma_fb(
    const float* __restrict__ keys, const float* __restrict__ queries,
    const float* __restrict__ values, const float* __restrict__ wW,
    const float* __restrict__ lsp, const float* __restrict__ dW,
    const float* __restrict__ db, const float* __restrict__ rW,
    const float* __restrict__ rb, float* __restrict__ out)
{
    __shared__ float atil[NK];
    __shared__ float btil[NK];
    __shared__ float ekl[NK];
    __shared__ float tot[64][66];
    __shared__ float esum_lds[64];
    __shared__ float qinfo[64][2];

    const int tid  = threadIdx.x;
    const int wave = tid >> 6;
    const int lane = tid & 63;
    const int g    = lane >> 4;
    const int l15  = lane & 15;
    const int wg   = wave >> 2;
    const int rt   = wave & 3;
    const int bid  = blockIdx.x;
    const int b    = bid & 7;
    const int q0   = (bid >> 3) * 64;

    const float W00 = wW[0], W01 = wW[1], W10 = wW[2], W11 = wW[3];
    const float xls = lsp[0] * 0.1f - 1.0f;
    const float sp  = (xls > 20.f) ? xls : log1pf(__expf(xls));
    const float sg  = 1e-5f + sp;
    const float s2  = (-0.5f / (sg * sg)) * LOG2E;

    {
        const float2* kb2 = (const float2*)(keys + (size_t)b * NK * 2);
        #pragma unroll
        for (int it = 0; it < NK / 512; ++it) {
            const int k = tid + it * 512;
            const float2 kv = kb2[k];
            const float a  = W00 * kv.x + W01 * kv.y;
            const float bb = W10 * kv.x + W11 * kv.y;
            atil[k] = -2.f * s2 * a;
            btil[k] = -2.f * s2 * bb;
            ekl[k]  = s2 * (a * a + bb * bb);
        }
    }
    const int q = q0 + rt * 16 + l15;
    const float2 qv = ((const float2*)(queries + (size_t)b * NQ * 2))[q];
    const float aq = W00 * qv.x + W01 * qv.y;
    const float bq = W10 * qv.x + W11 * qv.y;
    const float Fq = s2 * (aq * aq + bq * bq);
    __syncthreads();

    f32x4 c0 = {0.f, 0.f, 0.f, 0.f};
    f32x4 c1 = c0, c2 = c0, c3 = c0, ce = c0;
    const bf16x8 ones = { (short)0x3F80, (short)0x3F80, (short)0x3F80, (short)0x3F80,
                          (short)0x3F80, (short)0x3F80, (short)0x3F80, (short)0x3F80 };
    const float* vb = values + (size_t)b * NK * CIN;

    #pragma unroll 1
    for (int it = 0; it < NK / 64; ++it) {
        const int kb = it * 64 + wg * 32 + g * 8;
        FSCORE(0, e0) FSCORE(1, e1) FSCORE(2, e2) FSCORE(3, e3)
        FSCORE(4, e4) FSCORE(5, e5) FSCORE(6, e6) FSCORE(7, e7)
        bf16x8 af;
        af[0] = (short)f2bf(e0); af[1] = (short)f2bf(e1);
        af[2] = (short)f2bf(e2); af[3] = (short)f2bf(e3);
        af[4] = (short)f2bf(e4); af[5] = (short)f2bf(e5);
        af[6] = (short)f2bf(e6); af[7] = (short)f2bf(e7);
        const float* pB = vb + (size_t)kb * CIN + l15;
        FBLOAD(b0, 0) FBLOAD(b1, 1) FBLOAD(b2, 2) FBLOAD(b3, 3)
        c0 = __builtin_amdgcn_mfma_f32_16x16x32_bf16(af, b0, c0, 0, 0, 0);
        c1 = __builtin_amdgcn_mfma_f32_16x16x32_bf16(af, b1, c1, 0, 0, 0);
        c2 = __builtin_amdgcn_mfma_f32_16x16x32_bf16(af, b2, c2, 0, 0, 0);
        c3 = __builtin_amdgcn_mfma_f32_16x16x32_bf16(af, b3, c3, 0, 0, 0);
        ce = __builtin_amdgcn_mfma_f32_16x16x32_bf16(af, ones, ce, 0, 0, 0);
    }
    #define FSTORE_R(R)                                                       \
    {                                                                         \
        const int qq = rt * 16 + g * 4 + (R);                                 \
        tot[qq][0 * 16 + l15] = c0[R];                                        \
        tot[qq][1 * 16 + l15] = c1[R];                                        \
        tot[qq][2 * 16 + l15] = c2[R];                                        \
        tot[qq][3 * 16 + l15] = c3[R];                                        \
        if (l15 == 0) esum_lds[qq] = ce[R];                                   \
    }
    #define FADD_R(R)                                                         \
    {                                                                         \
        const int qq = rt * 16 + g * 4 + (R);                                 \
        tot[qq][0 * 16 + l15] += c0[R];                                       \
        tot[qq][1 * 16 + l15] += c1[R];                                       \
        tot[qq][2 * 16 + l15] += c2[R];                                       \
        tot[qq][3 * 16 + l15] += c3[R];                                       \
        if (l15 == 0) esum_lds[qq] += ce[R];                                  \
    }
    if (wg == 0) { FSTORE_R(0) FSTORE_R(1) FSTORE_R(2) FSTORE_R(3) }
    __syncthreads();
    if (wg == 1) { FADD_R(0) FADD_R(1) FADD_R(2) FADD_R(3) }
    __syncthreads();
    if (tid < 64) {
        const float s = esum_lds[tid];
        const float arg = ((-s) * dW[0] + db[0]) * 0.1f;
        qinfo[tid][1] = 1.f / (1.f + __expf(-arg));
        qinfo[tid][0] = 1.f / s;
    }
    __syncthreads();
    {
        const int qq   = tid >> 3;
        const float invE = qinfo[qq][0];
        const float dens = qinfo[qq][1];
        float* orow = out + (size_t)(b * NQ + q0 + qq) * COUT;
        #pragma unroll
        for (int r = 0; r < 8; ++r) {
            const int o = (tid & 7) + r * 8;
            const float* wrow = rW + o * (CIN + 1);
            float sdot = 0.f;
            #pragma unroll 8
            for (int c = 0; c < CIN; ++c) sdot += tot[qq][c] * wrow[c];
            orow[o] = rb[o] + dens * wrow[CIN] + sdot * invE;
        }
    }
}

extern "C" void kernel_launch(void* const* d_in, const int* in_sizes, int n_in,
                              void* d_out, int out_size, void* d_ws, size_t ws_size,
                              hipStream_t stream) {
    const float* keys    = (const float*)d_in[0];
    const float* queries = (const float*)d_in[1];
    const float* values  = (const float*)d_in[2];
    const float* wW      = (const float*)d_in[3];
    const float* lsp     = (const float*)d_in[4];
    const float* dW      = (const float*)d_in[5];
    const float* db      = (const float*)d_in[6];
    const float* rW      = (const float*)d_in[7];
    const float* rb      = (const float*)d_in[8];
    float* out = (float*)d_out;

    const size_t VF_BYTES    = (size_t)B * NK * CIN * 2;        // 2 MB
    const size_t COEFF_BYTES = (size_t)B * NK * 16;             // 512 KB
    const size_t NEED        = VF_BYTES + COEFF_BYTES;

    if (ws_size >= NEED) {
        unsigned short* vf = (unsigned short*)d_ws;
        float4* coeff = (float4*)((char*)d_ws + VF_BYTES);
        setconv_prepass<<<dim3(256), 256, 0, stream>>>(keys, values, wW, lsp, vf, coeff);
        setconv_main<<<dim3(512), 512, 0, stream>>>(queries, wW, lsp, dW, db,
                                                    rW, rb, vf, coeff, out);
    } else {
        setconv_mfma_fb<<<dim3(256), 512, 0, stream>>>(keys, queries, values, wW,
                                                       lsp, dW, db, rW, rb, out);
    }
}

// Round 8
// 42.888 us; speedup vs baseline: 1.9230x; 1.6042x over previous
//
#include <hip/hip_runtime.h>
#include <math.h>

#define B 8
#define NQ 2048
#define NK 2048
#define CIN 64
#define COUT 64

constexpr float LOG2E = 1.44269504088896340736f;

typedef __attribute__((ext_vector_type(8))) short bf16x8;
typedef __attribute__((ext_vector_type(4))) float f32x4;

__device__ __forceinline__ unsigned short f2bf(float x) {   // RNE f32->bf16
    union { float f; unsigned u; } v; v.f = x;
    return (unsigned short)((v.u + 0x7FFFu + ((v.u >> 16) & 1u)) >> 16);
}

// ------- pre-pass: V -> Vfrag[b][k/32][c][k%32] bf16 + packed coefficients --
// coeffP: per k-octet (8 keys): {a[8], b[8], E[8]} = 24 floats = 96 B
__global__ __launch_bounds__(256) void setconv_prepass(
    const float* __restrict__ keys,     // [B][NK][2]
    const float* __restrict__ values,   // [B][NK][CIN]
    const float* __restrict__ wW,
    const float* __restrict__ lsp,
    unsigned short* __restrict__ vf,    // [B][NK/32][CIN][32] bf16
    float* __restrict__ coeffP)         // [B][NK/8][24]
{
    __shared__ float lds[64][65];
    const int t   = threadIdx.x;
    const int bid = blockIdx.x;         // 256 = 8 batches x 32 k-tiles(64)
    const int b   = bid & 7;
    const int kt  = bid >> 3;

    // load 64k x 64c f32 tile, coalesced
    {
        const float* vbase = values + ((size_t)b * NK + (size_t)kt * 64) * CIN;
        const int r  = t >> 2;
        const int cq = t & 3;
        #pragma unroll
        for (int i = 0; i < 4; ++i) {
            const float4 v = *reinterpret_cast<const float4*>(
                vbase + r * CIN + cq * 16 + i * 4);
            lds[r][cq * 16 + i * 4 + 0] = v.x;
            lds[r][cq * 16 + i * 4 + 1] = v.y;
            lds[r][cq * 16 + i * 4 + 2] = v.z;
            lds[r][cq * 16 + i * 4 + 3] = v.w;
        }
    }

    // packed score coefficients for this tile's 64 keys
    if (t < 64) {
        const float W00 = wW[0], W01 = wW[1], W10 = wW[2], W11 = wW[3];
        const float xls = lsp[0] * 0.1f - 1.0f;
        const float sp  = (xls > 20.f) ? xls : log1pf(__expf(xls));
        const float sg  = 1e-5f + sp;
        const float s2  = (-0.5f / (sg * sg)) * LOG2E;
        const int   k   = kt * 64 + t;
        const float2 kv = reinterpret_cast<const float2*>(keys + (size_t)b * NK * 2)[k];
        const float a   = W00 * kv.x + W01 * kv.y;
        const float bb  = W10 * kv.x + W11 * kv.y;
        float* base = coeffP + ((size_t)b * (NK / 8) + (k >> 3)) * 24;
        const int j = k & 7;
        base[j]      = -2.f * s2 * a;
        base[8 + j]  = -2.f * s2 * bb;
        base[16 + j] = s2 * (a * a + bb * bb);
    }
    __syncthreads();

    // write fragment layout: vf[b][kt*2 + (kq>>1)][c][(kq&1)*16 + i]
    {
        const int c  = t >> 2;           // 0..63
        const int kq = t & 3;            // k-local range kq*16..+15
        unsigned pack[8];
        #pragma unroll
        for (int i = 0; i < 8; ++i) {
            const unsigned lo = f2bf(lds[kq * 16 + 2 * i + 0][c]);
            const unsigned hi = f2bf(lds[kq * 16 + 2 * i + 1][c]);
            pack[i] = lo | (hi << 16);
        }
        const size_t kblk = (size_t)kt * 2 + (kq >> 1);
        uint4* d4 = reinterpret_cast<uint4*>(
            vf + (((size_t)b * (NK / 32) + kblk) * CIN + c) * 32 + (kq & 1) * 16);
        d4[0] = make_uint4(pack[0], pack[1], pack[2], pack[3]);
        d4[1] = make_uint4(pack[4], pack[5], pack[6], pack[7]);
    }
}

// ---------------- main kernel: 512 blocks x 32 queries, k split 4-way --------
// Manual 2-stage software pipeline: named register sets A/B force the
// allocator to keep a full iteration of loads in flight (R7 showed VGPR=32
// => serialized load-use chains; this is the fix).

#define LOADC(S, IT_)                                                        \
  {                                                                          \
    const float* cptr = cpb + ((size_t)(((IT_) * 4 + wg) * 4 + g)) * 24;     \
    S##a0 = *reinterpret_cast<const f32x4*>(cptr + 0);                       \
    S##a1 = *reinterpret_cast<const f32x4*>(cptr + 4);                       \
    S##b0 = *reinterpret_cast<const f32x4*>(cptr + 8);                       \
    S##b1 = *reinterpret_cast<const f32x4*>(cptr + 12);                      \
    S##e0 = *reinterpret_cast<const f32x4*>(cptr + 16);                      \
    S##e1 = *reinterpret_cast<const f32x4*>(cptr + 20);                      \
  }

#define LOADV(S, IT_)                                                        \
  {                                                                          \
    const unsigned short* vptr =                                             \
        vfb + (((size_t)((IT_) * 4 + wg)) * CIN + l15) * 32 + g * 8;         \
    S##v0 = *reinterpret_cast<const bf16x8*>(vptr + 0 * 16 * 32);            \
    S##v1 = *reinterpret_cast<const bf16x8*>(vptr + 1 * 16 * 32);            \
    S##v2 = *reinterpret_cast<const bf16x8*>(vptr + 2 * 16 * 32);            \
    S##v3 = *reinterpret_cast<const bf16x8*>(vptr + 3 * 16 * 32);            \
  }

#define COMPUTE(S)                                                           \
  {                                                                          \
    const float t0 = fmaf(S##a0[0], aq, fmaf(S##b0[0], bq, S##e0[0] + Fq));  \
    const float t1 = fmaf(S##a0[1], aq, fmaf(S##b0[1], bq, S##e0[1] + Fq));  \
    const float t2 = fmaf(S##a0[2], aq, fmaf(S##b0[2], bq, S##e0[2] + Fq));  \
    const float t3 = fmaf(S##a0[3], aq, fmaf(S##b0[3], bq, S##e0[3] + Fq));  \
    const float t4 = fmaf(S##a1[0], aq, fmaf(S##b1[0], bq, S##e1[0] + Fq));  \
    const float t5 = fmaf(S##a1[1], aq, fmaf(S##b1[1], bq, S##e1[1] + Fq));  \
    const float t6 = fmaf(S##a1[2], aq, fmaf(S##b1[2], bq, S##e1[2] + Fq));  \
    const float t7 = fmaf(S##a1[3], aq, fmaf(S##b1[3], bq, S##e1[3] + Fq));  \
    bf16x8 af;                                                               \
    af[0] = (short)f2bf(exp2f(t0)); af[1] = (short)f2bf(exp2f(t1));          \
    af[2] = (short)f2bf(exp2f(t2)); af[3] = (short)f2bf(exp2f(t3));          \
    af[4] = (short)f2bf(exp2f(t4)); af[5] = (short)f2bf(exp2f(t5));          \
    af[6] = (short)f2bf(exp2f(t6)); af[7] = (short)f2bf(exp2f(t7));          \
    c0 = __builtin_amdgcn_mfma_f32_16x16x32_bf16(af, S##v0, c0, 0, 0, 0);    \
    c1 = __builtin_amdgcn_mfma_f32_16x16x32_bf16(af, S##v1, c1, 0, 0, 0);    \
    c2 = __builtin_amdgcn_mfma_f32_16x16x32_bf16(af, S##v2, c2, 0, 0, 0);    \
    c3 = __builtin_amdgcn_mfma_f32_16x16x32_bf16(af, S##v3, c3, 0, 0, 0);    \
    ce = __builtin_amdgcn_mfma_f32_16x16x32_bf16(af, ones, ce, 0, 0, 0);     \
  }

__global__ __launch_bounds__(512, 4) void setconv_main(
    const float* __restrict__ queries,  // [B][NQ][2]
    const float* __restrict__ wW,
    const float* __restrict__ lsp,
    const float* __restrict__ dW,
    const float* __restrict__ db,
    const float* __restrict__ rW,       // [COUT][CIN+1]
    const float* __restrict__ rb,       // [COUT]
    const unsigned short* __restrict__ vf,
    const float* __restrict__ coeffP,
    float* __restrict__ out)            // [B][NQ][COUT]
{
    __shared__ float pt[4][32][66];     // per-wg partial P*V (33.8 KB)
    __shared__ float rwl[65][64];       // rW^T staged (16.6 KB), lane=o stride-1
    __shared__ float esp[4][32];
    __shared__ float qinfo[32][2];      // inv_esum, density

    const int tid  = threadIdx.x;
    const int wave = tid >> 6;
    const int lane = tid & 63;
    const int g    = lane >> 4;
    const int l15  = lane & 15;
    const int wg   = wave >> 1;         // 0..3: k-group
    const int rt   = wave & 1;          // 0..1: 16-query row tile

    const int bid = blockIdx.x;         // 512 = 8 batches x 64 q-tiles
    const int b   = bid & 7;
    const int q0  = (bid >> 3) * 32;

    // stage rW^T: rwl[c][o]  (read coalesced, write conflicts negligible 1x)
    for (int idx = tid; idx < 65 * 64; idx += 512) {
        const int o = idx / 65;
        const int c = idx % 65;
        rwl[c][o] = rW[idx];
    }

    // per-lane query coefficients
    const float W00 = wW[0], W01 = wW[1], W10 = wW[2], W11 = wW[3];
    const float xls = lsp[0] * 0.1f - 1.0f;
    const float sp  = (xls > 20.f) ? xls : log1pf(__expf(xls));
    const float sg  = 1e-5f + sp;
    const float s2  = (-0.5f / (sg * sg)) * LOG2E;
    const int   q   = q0 + rt * 16 + l15;
    const float2 qv = reinterpret_cast<const float2*>(queries + (size_t)b * NQ * 2)[q];
    const float aq  = W00 * qv.x + W01 * qv.y;
    const float bq  = W10 * qv.x + W11 * qv.y;
    const float Fq  = s2 * (aq * aq + bq * bq);

    f32x4 c0 = {0.f, 0.f, 0.f, 0.f};
    f32x4 c1 = c0, c2 = c0, c3 = c0, ce = c0;
    const bf16x8 ones = { (short)0x3F80, (short)0x3F80, (short)0x3F80, (short)0x3F80,
                          (short)0x3F80, (short)0x3F80, (short)0x3F80, (short)0x3F80 };

    const unsigned short* vfb = vf + (size_t)b * (NK / 32) * CIN * 32;
    const float* cpb = coeffP + (size_t)b * (NK / 8) * 24;

    // pipeline registers (named => forced allocation)
    f32x4 Aa0, Aa1, Ab0, Ab1, Ae0, Ae1;  bf16x8 Av0, Av1, Av2, Av3;
    f32x4 Ba0, Ba1, Bb0, Bb1, Be0, Be1;  bf16x8 Bv0, Bv1, Bv2, Bv3;

    LOADC(A, 0) LOADV(A, 0)
    #pragma unroll 1
    for (int it = 0; it < 14; it += 2) {
        LOADC(B, it + 1) LOADV(B, it + 1)
        COMPUTE(A)
        LOADC(A, it + 2) LOADV(A, it + 2)
        COMPUTE(B)
    }
    LOADC(B, 15) LOADV(B, 15)
    COMPUTE(A)
    COMPUTE(B)

    // write per-wg partials.  C/D layout: col = l15, row = g*4 + reg
    #define STORE_R(R)                                                        \
    {                                                                         \
        const int qq = rt * 16 + g * 4 + (R);                                 \
        pt[wg][qq][0 * 16 + l15] = c0[R];                                     \
        pt[wg][qq][1 * 16 + l15] = c1[R];                                     \
        pt[wg][qq][2 * 16 + l15] = c2[R];                                     \
        pt[wg][qq][3 * 16 + l15] = c3[R];                                     \
        if (l15 == 0) esp[wg][qq] = ce[R];                                    \
    }
    STORE_R(0) STORE_R(1) STORE_R(2) STORE_R(3)
    __syncthreads();

    // combine 4 k-groups
    #pragma unroll
    for (int rr = 0; rr < 4; ++rr) {
        const int p  = tid + rr * 512;
        const int qq = p >> 6;
        const int cc = p & 63;
        const float s = pt[0][qq][cc] + pt[1][qq][cc] + pt[2][qq][cc] + pt[3][qq][cc];
        pt[0][qq][cc] = s;
    }
    if (tid < 32) {
        const float s = esp[0][tid] + esp[1][tid] + esp[2][tid] + esp[3][tid];
        const float arg = ((-s) * dW[0] + db[0]) * 0.1f;
        qinfo[tid][1] = 1.f / (1.f + __expf(-arg));   // density channel
        qinfo[tid][0] = 1.f / s;                      // softmax denom
    }
    __syncthreads();

    // fused resizer epilogue: lane = output channel o, wave covers 4 queries
    {
        const int o   = lane;
        const int qb  = wave * 4;
        const float rbo   = rb[o];
        const float wdens = rwl[64][o];
        float s0 = 0.f, s1 = 0.f, s2w = 0.f, s3 = 0.f;
        #pragma unroll
        for (int c = 0; c < 64; ++c) {
            const float w_ = rwl[c][o];
            s0  = fmaf(pt[0][qb + 0][c], w_, s0);
            s1  = fmaf(pt[0][qb + 1][c], w_, s1);
            s2w = fmaf(pt[0][qb + 2][c], w_, s2w);
            s3  = fmaf(pt[0][qb + 3][c], w_, s3);
        }
        float* obase = out + ((size_t)(b * NQ + q0 + qb)) * COUT + o;
        obase[0 * COUT] = rbo + qinfo[qb + 0][1] * wdens + s0  * qinfo[qb + 0][0];
        obase[1 * COUT] = rbo + qinfo[qb + 1][1] * wdens + s1  * qinfo[qb + 1][0];
        obase[2 * COUT] = rbo + qinfo[qb + 2][1] * wdens + s2w * qinfo[qb + 2][0];
        obase[3 * COUT] = rbo + qinfo[qb + 3][1] * wdens + s3  * qinfo[qb + 3][0];
    }
}

// ---------------- fallback (round-5 kernel, used if ws too small) -----------
#define FSCORE(J, EV)                                             \
    float EV;                                                     \
    {                                                             \
        float t_ = ekl[kb + (J)] + Fq;                            \
        t_ = fmaf(btil[kb + (J)], bq, t_);                        \
        t_ = fmaf(atil[kb + (J)], aq, t_);                        \
        EV = exp2f(t_);                                           \
    }
#define FBLOAD(BF, CT)                                            \
    bf16x8 BF;                                                    \
    BF[0] = (short)f2bf(pB[0 * CIN + (CT) * 16]);                 \
    BF[1] = (short)f2bf(pB[1 * CIN + (CT) * 16]);                 \
    BF[2] = (short)f2bf(pB[2 * CIN + (CT) * 16]);                 \
    BF[3] = (short)f2bf(pB[3 * CIN + (CT) * 16]);                 \
    BF[4] = (short)f2bf(pB[4 * CIN + (CT) * 16]);                 \
    BF[5] = (short)f2bf(pB[5 * CIN + (CT) * 16]);                 \
    BF[6] = (short)f2bf(pB[6 * CIN + (CT) * 16]);                 \
    BF[7] = (short)f2bf(pB[7 * CIN + (CT) * 16]);

__global__ __launch_bounds__(512) void setconv_mfma_fb(
    const float* __restrict__ keys, const float* __restrict__ queries,
    const float* __restrict__ values, const float* __restrict__ wW,
    const float* __restrict__ lsp, const float* __restrict__ dW,
    const float* __restrict__ db, const float* __restrict__ rW,
    const float* __restrict__ rb, float* __restrict__ out)
{
    __shared__ float atil[NK];
    __shared__ float btil[NK];
    __shared__ float ekl[NK];
    __shared__ float tot[64][66];
    __shared__ float esum_lds[64];
    __shared__ float qinfo[64][2];

    const int tid  = threadIdx.x;
    const int wave = tid >> 6;
    const int lane = tid & 63;
    const int g    = lane >> 4;
    const int l15  = lane & 15;
    const int wg   = wave >> 2;
    const int rt   = wave & 3;
    const int bid  = blockIdx.x;
    const int b    = bid & 7;
    const int q0   = (bid >> 3) * 64;

    const float W00 = wW[0], W01 = wW[1], W10 = wW[2], W11 = wW[3];
    const float xls = lsp[0] * 0.1f - 1.0f;
    const float sp  = (xls > 20.f) ? xls : log1pf(__expf(xls));
    const float sg  = 1e-5f + sp;
    const float s2  = (-0.5f / (sg * sg)) * LOG2E;

    {
        const float2* kb2 = (const float2*)(keys + (size_t)b * NK * 2);
        #pragma unroll
        for (int it = 0; it < NK / 512; ++it) {
            const int k = tid + it * 512;
            const float2 kv = kb2[k];
            const float a  = W00 * kv.x + W01 * kv.y;
            const float bb = W10 * kv.x + W11 * kv.y;
            atil[k] = -2.f * s2 * a;
            btil[k] = -2.f * s2 * bb;
            ekl[k]  = s2 * (a * a + bb * bb);
        }
    }
    const int q = q0 + rt * 16 + l15;
    const float2 qv = ((const float2*)(queries + (size_t)b * NQ * 2))[q];
    const float aq = W00 * qv.x + W01 * qv.y;
    const float bq = W10 * qv.x + W11 * qv.y;
    const float Fq = s2 * (aq * aq + bq * bq);
    __syncthreads();

    f32x4 c0 = {0.f, 0.f, 0.f, 0.f};
    f32x4 c1 = c0, c2 = c0, c3 = c0, ce = c0;
    const bf16x8 ones = { (short)0x3F80, (short)0x3F80, (short)0x3F80, (short)0x3F80,
                          (short)0x3F80, (short)0x3F80, (short)0x3F80, (short)0x3F80 };
    const float* vb = values + (size_t)b * NK * CIN;

    #pragma unroll 1
    for (int it = 0; it < NK / 64; ++it) {
        const int kb = it * 64 + wg * 32 + g * 8;
        FSCORE(0, e0) FSCORE(1, e1) FSCORE(2, e2) FSCORE(3, e3)
        FSCORE(4, e4) FSCORE(5, e5) FSCORE(6, e6) FSCORE(7, e7)
        bf16x8 af;
        af[0] = (short)f2bf(e0); af[1] = (short)f2bf(e1);
        af[2] = (short)f2bf(e2); af[3] = (short)f2bf(e3);
        af[4] = (short)f2bf(e4); af[5] = (short)f2bf(e5);
        af[6] = (short)f2bf(e6); af[7] = (short)f2bf(e7);
        const float* pB = vb + (size_t)kb * CIN + l15;
        FBLOAD(b0, 0) FBLOAD(b1, 1) FBLOAD(b2, 2) FBLOAD(b3, 3)
        c0 = __builtin_amdgcn_mfma_f32_16x16x32_bf16(af, b0, c0, 0, 0, 0);
        c1 = __builtin_amdgcn_mfma_f32_16x16x32_bf16(af, b1, c1, 0, 0, 0);
        c2 = __builtin_amdgcn_mfma_f32_16x16x32_bf16(af, b2, c2, 0, 0, 0);
        c3 = __builtin_amdgcn_mfma_f32_16x16x32_bf16(af, b3, c3, 0, 0, 0);
        ce = __builtin_amdgcn_mfma_f32_16x16x32_bf16(af, ones, ce, 0, 0, 0);
    }
    #define FSTORE_R(R)                                                       \
    {                                                                         \
        const int qq = rt * 16 + g * 4 + (R);                                 \
        tot[qq][0 * 16 + l15] = c0[R];                                        \
        tot[qq][1 * 16 + l15] = c1[R];                                        \
        tot[qq][2 * 16 + l15] = c2[R];                                        \
        tot[qq][3 * 16 + l15] = c3[R];                                        \
        if (l15 == 0) esum_lds[qq] = ce[R];                                   \
    }
    #define FADD_R(R)                                                         \
    {                                                                         \
        const int qq = rt * 16 + g * 4 + (R);                                 \
        tot[qq][0 * 16 + l15] += c0[R];                                       \
        tot[qq][1 * 16 + l15] += c1[R];                                       \
        tot[qq][2 * 16 + l15] += c2[R];                                       \
        tot[qq][3 * 16 + l15] += c3[R];                                       \
        if (l15 == 0) esum_lds[qq] += ce[R];                                  \
    }
    if (wg == 0) { FSTORE_R(0) FSTORE_R(1) FSTORE_R(2) FSTORE_R(3) }
    __syncthreads();
    if (wg == 1) { FADD_R(0) FADD_R(1) FADD_R(2) FADD_R(3) }
    __syncthreads();
    if (tid < 64) {
        const float s = esum_lds[tid];
        const float arg = ((-s) * dW[0] + db[0]) * 0.1f;
        qinfo[tid][1] = 1.f / (1.f + __expf(-arg));
        qinfo[tid][0] = 1.f / s;
    }
    __syncthreads();
    {
        const int qq   = tid >> 3;
        const float invE = qinfo[qq][0];
        const float dens = qinfo[qq][1];
        float* orow = out + (size_t)(b * NQ + q0 + qq) * COUT;
        #pragma unroll
        for (int r = 0; r < 8; ++r) {
            const int o = (tid & 7) + r * 8;
            const float* wrow = rW + o * (CIN + 1);
            float sdot = 0.f;
            #pragma unroll 8
            for (int c = 0; c < CIN; ++c) sdot += tot[qq][c] * wrow[c];
            orow[o] = rb[o] + dens * wrow[CIN] + sdot * invE;
        }
    }
}

extern "C" void kernel_launch(void* const* d_in, const int* in_sizes, int n_in,
                              void* d_out, int out_size, void* d_ws, size_t ws_size,
                              hipStream_t stream) {
    const float* keys    = (const float*)d_in[0];
    const float* queries = (const float*)d_in[1];
    const float* values  = (const float*)d_in[2];
    const float* wW      = (const float*)d_in[3];
    const float* lsp     = (const float*)d_in[4];
    const float* dW      = (const float*)d_in[5];
    const float* db      = (const float*)d_in[6];
    const float* rW      = (const float*)d_in[7];
    const float* rb      = (const float*)d_in[8];
    float* out = (float*)d_out;

    const size_t VF_BYTES    = (size_t)B * NK * CIN * 2;        // 2 MB
    const size_t COEFF_BYTES = (size_t)B * (NK / 8) * 24 * 4;   // 192 KB
    const size_t NEED        = VF_BYTES + COEFF_BYTES;

    if (ws_size >= NEED) {
        unsigned short* vf = (unsigned short*)d_ws;
        float* coeffP = (float*)((char*)d_ws + VF_BYTES);
        setconv_prepass<<<dim3(256), 256, 0, stream>>>(keys, values, wW, lsp, vf, coeffP);
        setconv_main<<<dim3(512), 512, 0, stream>>>(queries, wW, lsp, dW, db,
                                                    rW, rb, vf, coeffP, out);
    } else {
        setconv_mfma_fb<<<dim3(256), 512, 0, stream>>>(keys, queries, values, wW,
                                                       lsp, dW, db, rW, rb, out);
    }
}

// Round 9
// 31.994 us; speedup vs baseline: 2.5778x; 1.3405x over previous
//
#include <hip/hip_runtime.h>
#include <math.h>

#define B 8
#define NQ 2048
#define NK 2048
#define CIN 64
#define COUT 64

constexpr float LOG2E = 1.44269504088896340736f;

typedef __attribute__((ext_vector_type(8))) short bf16x8;
typedef __attribute__((ext_vector_type(4))) float f32x4;

__device__ __forceinline__ unsigned short f2bf(float x) {   // RNE f32->bf16
    union { float f; unsigned u; } v; v.f = x;
    return (unsigned short)((v.u + 0x7FFFu + ((v.u >> 16) & 1u)) >> 16);
}

// ------- pre-pass: V -> Vfrag[b][k/32][c][k%32] bf16 + packed coefficients --
// coeffP: per k-octet (8 keys): {a[8], b[8], E[8]} = 24 floats = 96 B
__global__ __launch_bounds__(256) void setconv_prepass(
    const float* __restrict__ keys,     // [B][NK][2]
    const float* __restrict__ values,   // [B][NK][CIN]
    const float* __restrict__ wW,
    const float* __restrict__ lsp,
    unsigned short* __restrict__ vf,    // [B][NK/32][CIN][32] bf16
    float* __restrict__ coeffP)         // [B][NK/8][24]
{
    __shared__ float lds[64][65];
    const int t   = threadIdx.x;
    const int bid = blockIdx.x;         // 256 = 8 batches x 32 k-tiles(64)
    const int b   = bid & 7;
    const int kt  = bid >> 3;

    // load 64k x 64c f32 tile, coalesced
    {
        const float* vbase = values + ((size_t)b * NK + (size_t)kt * 64) * CIN;
        const int r  = t >> 2;
        const int cq = t & 3;
        #pragma unroll
        for (int i = 0; i < 4; ++i) {
            const float4 v = *reinterpret_cast<const float4*>(
                vbase + r * CIN + cq * 16 + i * 4);
            lds[r][cq * 16 + i * 4 + 0] = v.x;
            lds[r][cq * 16 + i * 4 + 1] = v.y;
            lds[r][cq * 16 + i * 4 + 2] = v.z;
            lds[r][cq * 16 + i * 4 + 3] = v.w;
        }
    }

    // packed score coefficients for this tile's 64 keys
    if (t < 64) {
        const float W00 = wW[0], W01 = wW[1], W10 = wW[2], W11 = wW[3];
        const float xls = lsp[0] * 0.1f - 1.0f;
        const float sp  = (xls > 20.f) ? xls : log1pf(__expf(xls));
        const float sg  = 1e-5f + sp;
        const float s2  = (-0.5f / (sg * sg)) * LOG2E;
        const int   k   = kt * 64 + t;
        const float2 kv = reinterpret_cast<const float2*>(keys + (size_t)b * NK * 2)[k];
        const float a   = W00 * kv.x + W01 * kv.y;
        const float bb  = W10 * kv.x + W11 * kv.y;
        float* base = coeffP + ((size_t)b * (NK / 8) + (k >> 3)) * 24;
        const int j = k & 7;
        base[j]      = -2.f * s2 * a;
        base[8 + j]  = -2.f * s2 * bb;
        base[16 + j] = s2 * (a * a + bb * bb);
    }
    __syncthreads();

    // write fragment layout: vf[b][kt*2 + (kq>>1)][c][(kq&1)*16 + i]
    {
        const int c  = t >> 2;           // 0..63
        const int kq = t & 3;            // k-local range kq*16..+15
        unsigned pack[8];
        #pragma unroll
        for (int i = 0; i < 8; ++i) {
            const unsigned lo = f2bf(lds[kq * 16 + 2 * i + 0][c]);
            const unsigned hi = f2bf(lds[kq * 16 + 2 * i + 1][c]);
            pack[i] = lo | (hi << 16);
        }
        const size_t kblk = (size_t)kt * 2 + (kq >> 1);
        uint4* d4 = reinterpret_cast<uint4*>(
            vf + (((size_t)b * (NK / 32) + kblk) * CIN + c) * 32 + (kq & 1) * 16);
        d4[0] = make_uint4(pack[0], pack[1], pack[2], pack[3]);
        d4[1] = make_uint4(pack[4], pack[5], pack[6], pack[7]);
    }
}

// ---------------- main kernel: 512 blocks x 32 queries, k split 4-way --------
// V: 3-deep named-register global pipeline (vmcnt).  Coeff: staged in LDS at
// block start, read per-step via broadcast ds_read_b128 (lgkmcnt) — decoupled
// latency domains.

#define LOADVG(S, IT_)                                                       \
  {                                                                          \
    const unsigned short* vptr =                                             \
        vfb + (((size_t)((IT_) * 4 + wg)) * CIN + l15) * 32 + g * 8;         \
    S##0 = *reinterpret_cast<const bf16x8*>(vptr + 0 * 16 * 32);             \
    S##1 = *reinterpret_cast<const bf16x8*>(vptr + 1 * 16 * 32);             \
    S##2 = *reinterpret_cast<const bf16x8*>(vptr + 2 * 16 * 32);             \
    S##3 = *reinterpret_cast<const bf16x8*>(vptr + 3 * 16 * 32);             \
  }

#define STEP(S, IT_)                                                         \
  {                                                                          \
    const float* cl = coeffL + (size_t)((((IT_) * 4 + wg) * 4 + g)) * 24;    \
    const f32x4 ca0 = *reinterpret_cast<const f32x4*>(cl + 0);               \
    const f32x4 ca1 = *reinterpret_cast<const f32x4*>(cl + 4);               \
    const f32x4 cb0 = *reinterpret_cast<const f32x4*>(cl + 8);               \
    const f32x4 cb1 = *reinterpret_cast<const f32x4*>(cl + 12);              \
    const f32x4 ce0 = *reinterpret_cast<const f32x4*>(cl + 16);              \
    const f32x4 ce1 = *reinterpret_cast<const f32x4*>(cl + 20);              \
    const float t0 = fmaf(ca0[0], aq, fmaf(cb0[0], bq, ce0[0] + Fq));        \
    const float t1 = fmaf(ca0[1], aq, fmaf(cb0[1], bq, ce0[1] + Fq));        \
    const float t2 = fmaf(ca0[2], aq, fmaf(cb0[2], bq, ce0[2] + Fq));        \
    const float t3 = fmaf(ca0[3], aq, fmaf(cb0[3], bq, ce0[3] + Fq));        \
    const float t4 = fmaf(ca1[0], aq, fmaf(cb1[0], bq, ce1[0] + Fq));        \
    const float t5 = fmaf(ca1[1], aq, fmaf(cb1[1], bq, ce1[1] + Fq));        \
    const float t6 = fmaf(ca1[2], aq, fmaf(cb1[2], bq, ce1[2] + Fq));        \
    const float t7 = fmaf(ca1[3], aq, fmaf(cb1[3], bq, ce1[3] + Fq));        \
    bf16x8 af;                                                               \
    af[0] = (short)f2bf(exp2f(t0)); af[1] = (short)f2bf(exp2f(t1));          \
    af[2] = (short)f2bf(exp2f(t2)); af[3] = (short)f2bf(exp2f(t3));          \
    af[4] = (short)f2bf(exp2f(t4)); af[5] = (short)f2bf(exp2f(t5));          \
    af[6] = (short)f2bf(exp2f(t6)); af[7] = (short)f2bf(exp2f(t7));          \
    c0 = __builtin_amdgcn_mfma_f32_16x16x32_bf16(af, S##0, c0, 0, 0, 0);     \
    c1 = __builtin_amdgcn_mfma_f32_16x16x32_bf16(af, S##1, c1, 0, 0, 0);     \
    c2 = __builtin_amdgcn_mfma_f32_16x16x32_bf16(af, S##2, c2, 0, 0, 0);     \
    c3 = __builtin_amdgcn_mfma_f32_16x16x32_bf16(af, S##3, c3, 0, 0, 0);     \
    ce = __builtin_amdgcn_mfma_f32_16x16x32_bf16(af, ones, ce, 0, 0, 0);     \
  }

__global__ __launch_bounds__(512, 4) void setconv_main(
    const float* __restrict__ queries,  // [B][NQ][2]
    const float* __restrict__ wW,
    const float* __restrict__ lsp,
    const float* __restrict__ dW,
    const float* __restrict__ db,
    const float* __restrict__ rW,       // [COUT][CIN+1]
    const float* __restrict__ rb,       // [COUT]
    const unsigned short* __restrict__ vf,
    const float* __restrict__ coeffP,
    float* __restrict__ out)            // [B][NQ][COUT]
{
    __shared__ float coeffL[NK / 8 * 24];  // 24 KB packed coefficients
    __shared__ float pt[4][32][66];        // per-wg partial P*V (33.8 KB)
    __shared__ float rwl[65][65];          // rW^T staged, padded (16.9 KB)
    __shared__ float esp[4][32];
    __shared__ float qinfo[32][2];         // inv_esum, density

    const int tid  = threadIdx.x;
    const int wave = tid >> 6;
    const int lane = tid & 63;
    const int g    = lane >> 4;
    const int l15  = lane & 15;
    const int wg   = wave >> 1;         // 0..3: k-group
    const int rt   = wave & 1;          // 0..1: 16-query row tile

    const int bid = blockIdx.x;         // 512 = 8 batches x 64 q-tiles
    const int b   = bid & 7;
    const int q0  = (bid >> 3) * 32;

    const unsigned short* vfb = vf + (size_t)b * (NK / 32) * CIN * 32;

    // pipeline registers (named => forced allocation)
    bf16x8 Va0, Va1, Va2, Va3, Vb0, Vb1, Vb2, Vb3, Vc0, Vc1, Vc2, Vc3;

    // issue first two V-load groups before the staging barrier
    LOADVG(Va, 0)
    LOADVG(Vb, 1)

    // stage coeff (24 KB, coalesced float4) and rW^T (padded, conflict-free)
    {
        const float4* gsrc = reinterpret_cast<const float4*>(
            coeffP + (size_t)b * (NK / 8) * 24);
        float4* ldst = reinterpret_cast<float4*>(coeffL);
        #pragma unroll
        for (int i = 0; i < 3; ++i) ldst[tid + i * 512] = gsrc[tid + i * 512];
        for (int idx = tid; idx < 65 * 64; idx += 512) {
            const int o = idx / 65;
            const int c = idx % 65;
            rwl[c][o] = rW[idx];
        }
    }

    // per-lane query coefficients
    const float W00 = wW[0], W01 = wW[1], W10 = wW[2], W11 = wW[3];
    const float xls = lsp[0] * 0.1f - 1.0f;
    const float sp  = (xls > 20.f) ? xls : log1pf(__expf(xls));
    const float sg  = 1e-5f + sp;
    const float s2  = (-0.5f / (sg * sg)) * LOG2E;
    const int   q   = q0 + rt * 16 + l15;
    const float2 qv = reinterpret_cast<const float2*>(queries + (size_t)b * NQ * 2)[q];
    const float aq  = W00 * qv.x + W01 * qv.y;
    const float bq  = W10 * qv.x + W11 * qv.y;
    const float Fq  = s2 * (aq * aq + bq * bq);

    f32x4 c0 = {0.f, 0.f, 0.f, 0.f};
    f32x4 c1 = c0, c2 = c0, c3 = c0, ce = c0;
    const bf16x8 ones = { (short)0x3F80, (short)0x3F80, (short)0x3F80, (short)0x3F80,
                          (short)0x3F80, (short)0x3F80, (short)0x3F80, (short)0x3F80 };

    __syncthreads();   // coeffL/rwl ready

    // 16 K-steps, V 3-deep, coeff from LDS
    #pragma unroll 1
    for (int t = 0; t < 12; t += 3) {
        LOADVG(Vc, t + 2) STEP(Va, t)
        LOADVG(Va, t + 3) STEP(Vb, t + 1)
        LOADVG(Vb, t + 4) STEP(Vc, t + 2)
    }
    LOADVG(Vc, 14) STEP(Va, 12)
    LOADVG(Va, 15) STEP(Vb, 13)
    STEP(Vc, 14)
    STEP(Va, 15)

    // write per-wg partials.  C/D layout: col = l15, row = g*4 + reg
    #define STORE_R(R)                                                        \
    {                                                                         \
        const int qq = rt * 16 + g * 4 + (R);                                 \
        pt[wg][qq][0 * 16 + l15] = c0[R];                                     \
        pt[wg][qq][1 * 16 + l15] = c1[R];                                     \
        pt[wg][qq][2 * 16 + l15] = c2[R];                                     \
        pt[wg][qq][3 * 16 + l15] = c3[R];                                     \
        if (l15 == 0) esp[wg][qq] = ce[R];                                    \
    }
    STORE_R(0) STORE_R(1) STORE_R(2) STORE_R(3)
    __syncthreads();

    // combine 4 k-groups
    #pragma unroll
    for (int rr = 0; rr < 4; ++rr) {
        const int p  = tid + rr * 512;
        const int qq = p >> 6;
        const int cc = p & 63;
        const float s = pt[0][qq][cc] + pt[1][qq][cc] + pt[2][qq][cc] + pt[3][qq][cc];
        pt[0][qq][cc] = s;
    }
    if (tid < 32) {
        const float s = esp[0][tid] + esp[1][tid] + esp[2][tid] + esp[3][tid];
        const float arg = ((-s) * dW[0] + db[0]) * 0.1f;
        qinfo[tid][1] = 1.f / (1.f + __expf(-arg));   // density channel
        qinfo[tid][0] = 1.f / s;                      // softmax denom
    }
    __syncthreads();

    // fused resizer epilogue: lane = output channel o, wave covers 4 queries
    {
        const int o   = lane;
        const int qb  = wave * 4;
        const float rbo   = rb[o];
        const float wdens = rwl[64][o];
        float s0 = 0.f, s1 = 0.f, s2w = 0.f, s3 = 0.f;
        #pragma unroll
        for (int c = 0; c < 64; ++c) {
            const float w_ = rwl[c][o];
            s0  = fmaf(pt[0][qb + 0][c], w_, s0);
            s1  = fmaf(pt[0][qb + 1][c], w_, s1);
            s2w = fmaf(pt[0][qb + 2][c], w_, s2w);
            s3  = fmaf(pt[0][qb + 3][c], w_, s3);
        }
        float* obase = out + ((size_t)(b * NQ + q0 + qb)) * COUT + o;
        obase[0 * COUT] = rbo + qinfo[qb + 0][1] * wdens + s0  * qinfo[qb + 0][0];
        obase[1 * COUT] = rbo + qinfo[qb + 1][1] * wdens + s1  * qinfo[qb + 1][0];
        obase[2 * COUT] = rbo + qinfo[qb + 2][1] * wdens + s2w * qinfo[qb + 2][0];
        obase[3 * COUT] = rbo + qinfo[qb + 3][1] * wdens + s3  * qinfo[qb + 3][0];
    }
}

// ---------------- fallback (round-5 kernel, used if ws too small) -----------
#define FSCORE(J, EV)                                             \
    float EV;                                                     \
    {                                                             \
        float t_ = ekl[kb + (J)] + Fq;                            \
        t_ = fmaf(btil[kb + (J)], bq, t_);                        \
        t_ = fmaf(atil[kb + (J)], aq, t_);                        \
        EV = exp2f(t_);                                           \
    }
#define FBLOAD(BF, CT)                                            \
    bf16x8 BF;                                                    \
    BF[0] = (short)f2bf(pB[0 * CIN + (CT) * 16]);                 \
    BF[1] = (short)f2bf(pB[1 * CIN + (CT) * 16]);                 \
    BF[2] = (short)f2bf(pB[2 * CIN + (CT) * 16]);                 \
    BF[3] = (short)f2bf(pB[3 * CIN + (CT) * 16]);                 \
    BF[4] = (short)f2bf(pB[4 * CIN + (CT) * 16]);                 \
    BF[5] = (short)f2bf(pB[5 * CIN + (CT) * 16]);                 \
    BF[6] = (short)f2bf(pB[6 * CIN + (CT) * 16]);                 \
    BF[7] = (short)f2bf(pB[7 * CIN + (CT) * 16]);

__global__ __launch_bounds__(512) void setconv_mfma_fb(
    const float* __restrict__ keys, const float* __restrict__ queries,
    const float* __restrict__ values, const float* __restrict__ wW,
    const float* __restrict__ lsp, const float* __restrict__ dW,
    const float* __restrict__ db, const float* __restrict__ rW,
    const float* __restrict__ rb, float* __restrict__ out)
{
    __shared__ float atil[NK];
    __shared__ float btil[NK];
    __shared__ float ekl[NK];
    __shared__ float tot[64][66];
    __shared__ float esum_lds[64];
    __shared__ float qinfo[64][2];

    const int tid  = threadIdx.x;
    const int wave = tid >> 6;
    const int lane = tid & 63;
    const int g    = lane >> 4;
    const int l15  = lane & 15;
    const int wg   = wave >> 2;
    const int rt   = wave & 3;
    const int bid  = blockIdx.x;
    const int b    = bid & 7;
    const int q0   = (bid >> 3) * 64;

    const float W00 = wW[0], W01 = wW[1], W10 = wW[2], W11 = wW[3];
    const float xls = lsp[0] * 0.1f - 1.0f;
    const float sp  = (xls > 20.f) ? xls : log1pf(__expf(xls));
    const float sg  = 1e-5f + sp;
    const float s2  = (-0.5f / (sg * sg)) * LOG2E;

    {
        const float2* kb2 = (const float2*)(keys + (size_t)b * NK * 2);
        #pragma unroll
        for (int it = 0; it < NK / 512; ++it) {
            const int k = tid + it * 512;
            const float2 kv = kb2[k];
            const float a  = W00 * kv.x + W01 * kv.y;
            const float bb = W10 * kv.x + W11 * kv.y;
            atil[k] = -2.f * s2 * a;
            btil[k] = -2.f * s2 * bb;
            ekl[k]  = s2 * (a * a + bb * bb);
        }
    }
    const int q = q0 + rt * 16 + l15;
    const float2 qv = ((const float2*)(queries + (size_t)b * NQ * 2))[q];
    const float aq = W00 * qv.x + W01 * qv.y;
    const float bq = W10 * qv.x + W11 * qv.y;
    const float Fq = s2 * (aq * aq + bq * bq);
    __syncthreads();

    f32x4 c0 = {0.f, 0.f, 0.f, 0.f};
    f32x4 c1 = c0, c2 = c0, c3 = c0, ce = c0;
    const bf16x8 ones = { (short)0x3F80, (short)0x3F80, (short)0x3F80, (short)0x3F80,
                          (short)0x3F80, (short)0x3F80, (short)0x3F80, (short)0x3F80 };
    const float* vb = values + (size_t)b * NK * CIN;

    #pragma unroll 1
    for (int it = 0; it < NK / 64; ++it) {
        const int kb = it * 64 + wg * 32 + g * 8;
        FSCORE(0, e0) FSCORE(1, e1) FSCORE(2, e2) FSCORE(3, e3)
        FSCORE(4, e4) FSCORE(5, e5) FSCORE(6, e6) FSCORE(7, e7)
        bf16x8 af;
        af[0] = (short)f2bf(e0); af[1] = (short)f2bf(e1);
        af[2] = (short)f2bf(e2); af[3] = (short)f2bf(e3);
        af[4] = (short)f2bf(e4); af[5] = (short)f2bf(e5);
        af[6] = (short)f2bf(e6); af[7] = (short)f2bf(e7);
        const float* pB = vb + (size_t)kb * CIN + l15;
        FBLOAD(b0, 0) FBLOAD(b1, 1) FBLOAD(b2, 2) FBLOAD(b3, 3)
        c0 = __builtin_amdgcn_mfma_f32_16x16x32_bf16(af, b0, c0, 0, 0, 0);
        c1 = __builtin_amdgcn_mfma_f32_16x16x32_bf16(af, b1, c1, 0, 0, 0);
        c2 = __builtin_amdgcn_mfma_f32_16x16x32_bf16(af, b2, c2, 0, 0, 0);
        c3 = __builtin_amdgcn_mfma_f32_16x16x32_bf16(af, b3, c3, 0, 0, 0);
        ce = __builtin_amdgcn_mfma_f32_16x16x32_bf16(af, ones, ce, 0, 0, 0);
    }
    #define FSTORE_R(R)                                                       \
    {                                                                         \
        const int qq = rt * 16 + g * 4 + (R);                                 \
        tot[qq][0 * 16 + l15] = c0[R];                                        \
        tot[qq][1 * 16 + l15] = c1[R];                                        \
        tot[qq][2 * 16 + l15] = c2[R];                                        \
        tot[qq][3 * 16 + l15] = c3[R];                                        \
        if (l15 == 0) esum_lds[qq] = ce[R];                                   \
    }
    #define FADD_R(R)                                                         \
    {                                                                         \
        const int qq = rt * 16 + g * 4 + (R);                                 \
        tot[qq][0 * 16 + l15] += c0[R];                                       \
        tot[qq][1 * 16 + l15] += c1[R];                                       \
        tot[qq][2 * 16 + l15] += c2[R];                                       \
        tot[qq][3 * 16 + l15] += c3[R];                                       \
        if (l15 == 0) esum_lds[qq] += ce[R];                                  \
    }
    if (wg == 0) { FSTORE_R(0) FSTORE_R(1) FSTORE_R(2) FSTORE_R(3) }
    __syncthreads();
    if (wg == 1) { FADD_R(0) FADD_R(1) FADD_R(2) FADD_R(3) }
    __syncthreads();
    if (tid < 64) {
        const float s = esum_lds[tid];
        const float arg = ((-s) * dW[0] + db[0]) * 0.1f;
        qinfo[tid][1] = 1.f / (1.f + __expf(-arg));
        qinfo[tid][0] = 1.f / s;
    }
    __syncthreads();
    {
        const int qq   = tid >> 3;
        const float invE = qinfo[qq][0];
        const float dens = qinfo[qq][1];
        float* orow = out + (size_t)(b * NQ + q0 + qq) * COUT;
        #pragma unroll
        for (int r = 0; r < 8; ++r) {
            const int o = (tid & 7) + r * 8;
            const float* wrow = rW + o * (CIN + 1);
            float sdot = 0.f;
            #pragma unroll 8
            for (int c = 0; c < CIN; ++c) sdot += tot[qq][c] * wrow[c];
            orow[o] = rb[o] + dens * wrow[CIN] + sdot * invE;
        }
    }
}

extern "C" void kernel_launch(void* const* d_in, const int* in_sizes, int n_in,
                              void* d_out, int out_size, void* d_ws, size_t ws_size,
                              hipStream_t stream) {
    const float* keys    = (const float*)d_in[0];
    const float* queries = (const float*)d_in[1];
    const float* values  = (const float*)d_in[2];
    const float* wW      = (const float*)d_in[3];
    const float* lsp     = (const float*)d_in[4];
    const float* dW      = (const float*)d_in[5];
    const float* db      = (const float*)d_in[6];
    const float* rW      = (const float*)d_in[7];
    const float* rb      = (const float*)d_in[8];
    float* out = (float*)d_out;

    const size_t VF_BYTES    = (size_t)B * NK * CIN * 2;        // 2 MB
    const size_t COEFF_BYTES = (size_t)B * (NK / 8) * 24 * 4;   // 192 KB
    const size_t NEED        = VF_BYTES + COEFF_BYTES;

    if (ws_size >= NEED) {
        unsigned short* vf = (unsigned short*)d_ws;
        float* coeffP = (float*)((char*)d_ws + VF_BYTES);
        setconv_prepass<<<dim3(256), 256, 0, stream>>>(keys, values, wW, lsp, vf, coeffP);
        setconv_main<<<dim3(512), 512, 0, stream>>>(queries, wW, lsp, dW, db,
                                                    rW, rb, vf, coeffP, out);
    } else {
        setconv_mfma_fb<<<dim3(256), 512, 0, stream>>>(keys, queries, values, wW,
                                                       lsp, dW, db, rW, rb, out);
    }
}